// Round 6
// baseline (277.262 us; speedup 1.0000x reference)
//
#include <hip/hip_runtime.h>
#include <hip/hip_bf16.h>
#include <hip/hip_cooperative_groups.h>

namespace cg = cooperative_groups;

typedef __hip_bfloat16 bf16;
typedef short bf16x8 __attribute__((ext_vector_type(8)));
typedef float f32x4 __attribute__((ext_vector_type(4)));

#define S_LEN 4096
#define NBATCH 2
#define EDIM 1024
#define DDIM 64
#define MROWS (NBATCH * S_LEN)   // 8192

#define GLOBAL_AS __attribute__((address_space(1)))
#define LDS_AS __attribute__((address_space(3)))

union frag_u { bf16x8 v; bf16 e[8]; };

// async 16B global -> LDS (dest wave-uniform; HW adds lane*16; src per-lane)
__device__ __forceinline__ void async_ld16(const void* gp, void* lp) {
  __builtin_amdgcn_global_load_lds((const GLOBAL_AS void*)gp,
                                   (LDS_AS void*)lp, 16, 0, 0);
}

// f32x8 -> split bf16 hi/lo fragments (x ~= hi + lo, rel err ~2^-17)
__device__ __forceinline__ void cvt_split(const float4& a, const float4& b,
                                          bf16x8& hi, bf16x8& lo) {
  float v[8] = {a.x, a.y, a.z, a.w, b.x, b.y, b.z, b.w};
  frag_u h, l;
#pragma unroll
  for (int e = 0; e < 8; e++) {
    bf16 hh = __float2bfloat16(v[e]);
    h.e[e] = hh;
    l.e[e] = __float2bfloat16(v[e] - __bfloat162float(hh));
  }
  hi = h.v;
  lo = l.v;
}

// ---------------------------------------------------------------------------
// FUSED cooperative kernel v11 — pack | qkv-gemm | attn in ONE dispatch.
// R5 post-mortem: ~31 us of pack+attn+launch-gaps has been constant since R0
// and invisible (all kernels < the 43-us workspace-poison fills in top-k).
// Fusion: (a) kills 2 launch gaps, (b) overlaps A-panel DMA with pack+sync,
// (c) Q never touches global (stays in LDS; attn block == gemm block rows),
// (d) K/V window reads are same-XCD L2-hot via XCD-chunked row mapping,
// (e) the whole op becomes one >40us dispatch => visible counters.
// Grid 256 x 512 thr, 144 KB LDS, 1 block/CU (cooperative co-residency ok).
// Phase A: issue 16x 1-KB-burst A-DMAs (v10 pattern); blocks 0-47 also pack
//          weights (512-thr variant); block 0 zeroes Vsum. fence + grid.sync.
// Phase B: v10 K-loop verbatim (B reg ring-3 from packed Wt2, swizzled
//          ds_read A-frags, 18 MFMA/round, no barriers); kh-merge via LDS;
//          epilogue: Q (+bias) -> LDS, K/V (+bias) -> global, Vsum atomics.
//          fence + grid.sync.  NO early returns (cooperative).
// Phase C: attn, 32 q/block (16 lanes/q, float4/lane): 5 window scores via
//          4x shfl_xor reduce, full-row softmax collapsed to 5 exps +
//          background term (Vsum - window V), out = float4 store.
// MFMA f32_16x16x32_bf16 split-bf16 (xh*wh + xh*wl + xl*wh):
//   A[m][k]: m=lane&15, k=(lane>>4)*8+e | B[k][n]: n=lane&15, k=(lane>>4)*8+e
//   D[m][n]: m=(lane>>4)*4+r, n=lane&15
// ---------------------------------------------------------------------------
__global__ __launch_bounds__(512, 2) void fused_kernel(
    const float* __restrict__ x, const float* __restrict__ Wq,
    const float* __restrict__ bq, const float* __restrict__ Wk,
    const float* __restrict__ bk, const float* __restrict__ Wv,
    const float* __restrict__ bv, bf16* __restrict__ Wt2_hi,
    bf16* __restrict__ Wt2_lo, float* __restrict__ qkv,
    float* __restrict__ Vsum, float* __restrict__ out) {
  __shared__ __align__(16) char lds[147712];  // 128K A-panel + 16.6K pack tile
  const int tid = threadIdx.x;
  const int lane = tid & 63;
  const int wave = tid >> 6;                  // 0..7
  const int nh = wave & 3;
  const int kh = wave >> 2;
  const int quad = lane >> 4;
  const int l16 = lane & 15;
  // XCD-chunked bijective row-block mapping: XCD x owns contiguous vb range
  const int vb = ((blockIdx.x & 7) << 5) | (blockIdx.x >> 3);
  const int rowBase = vb * 32;

  // ---- Phase A0: issue this block's A-panel DMAs (16 x 1-KB row bursts)
#pragma unroll
  for (int i = 0; i < 16; i++) {
    const int Rl = (wave << 2) | (i >> 2);
    const int g = i & 3;
    const char* src = (const char*)x + (size_t)(rowBase + Rl) * 4096 +
                      (size_t)g * 1024 + ((lane ^ (Rl & 7)) << 4);
    async_ld16(src, lds + Rl * 4096 + g * 1024);
  }

  // ---- Phase A1: blocks 0-47 pack weights (512-thread variant of pack_w)
  if (blockIdx.x < 48) {
    float* tile = (float*)(lds + 131072);
    const int mat = blockIdx.x >> 4;
    const int kb = blockIdx.x & 15;
    const float* W = (mat == 0) ? Wq : ((mat == 1) ? Wk : Wv);
#pragma unroll
    for (int i2 = 0; i2 < 2; i2++) {
      int F = (i2 * 512 + tid) * 4;           // flat f32 idx in [0,4096)
      int k = F >> 6;
      int n4 = F & 63;
      float4 v =
          *(const float4*)(const void*)(W + (size_t)(kb * 64 + k) * 64 + n4);
      tile[(n4 + 0) * 65 + k] = v.x;
      tile[(n4 + 1) * 65 + k] = v.y;
      tile[(n4 + 2) * 65 + k] = v.z;
      tile[(n4 + 3) * 65 + k] = v.w;
    }
    __syncthreads();
    {
      int nl = tid >> 3;
      int j_half = (tid >> 2) & 1;
      int pp_k = tid & 3;
      int ng = mat * 64 + nl;
      int n2 = ng >> 1;
      int sp = ((ng & 1) * 4 + pp_k) ^ (n2 & 7);
      int unit = n2 * 8 + sp;
      int jp = kb * 2 + j_half;
      frag_u h, l;
#pragma unroll
      for (int e = 0; e < 8; e++) {
        float v = tile[nl * 65 + j_half * 32 + pp_k * 8 + e];
        bf16 hh = __float2bfloat16(v);
        h.e[e] = hh;
        l.e[e] = __float2bfloat16(v - __bfloat162float(hh));
      }
      size_t ob = (size_t)jp * 6144 + unit * 8;
      *(bf16x8*)(void*)(Wt2_hi + ob) = h.v;
      *(bf16x8*)(void*)(Wt2_lo + ob) = l.v;
    }
  }
  if (blockIdx.x == 0 && tid < NBATCH * DDIM) Vsum[tid] = 0.f;
  __threadfence();                            // release Wt2/Vsum to device
  cg::this_grid().sync();

  // ---- Phase B: QKV GEMM (v10 structure) --------------------------------
  const int sp = ((l16 & 1) * 4 + quad) ^ ((l16 >> 1) & 7);
  const int loff = ((l16 >> 1) * 8 + sp) * 8;
  const bf16* bhp = Wt2_hi + (size_t)kh * 98304 + nh * 1536 + loff;
  const bf16* blp = Wt2_lo + (size_t)kh * 98304 + nh * 1536 + loff;

  bf16x8 Bh[3][3], Bl[3][3];
  f32x4 acc[2][3];
#pragma unroll
  for (int f = 0; f < 2; f++)
#pragma unroll
    for (int t = 0; t < 3; t++) acc[f][t] = (f32x4){0.f, 0.f, 0.f, 0.f};

#define LOADB(s, r)                                                          \
  {                                                                          \
    const bf16* _h = bhp + (size_t)(r) * 6144;                               \
    const bf16* _l = blp + (size_t)(r) * 6144;                               \
    Bh[s][0] = *(const bf16x8*)(const void*)(_h);                            \
    Bh[s][1] = *(const bf16x8*)(const void*)(_h + 512);                      \
    Bh[s][2] = *(const bf16x8*)(const void*)(_h + 1024);                     \
    Bl[s][0] = *(const bf16x8*)(const void*)(_l);                            \
    Bl[s][1] = *(const bf16x8*)(const void*)(_l + 512);                      \
    Bl[s][2] = *(const bf16x8*)(const void*)(_l + 1024);                     \
  }

  LOADB(0, 0);
  LOADB(1, 1);
  LOADB(2, 2);
  asm volatile("s_waitcnt vmcnt(18)" ::: "memory");  // A-DMAs certainly in
  __builtin_amdgcn_s_barrier();
  __builtin_amdgcn_sched_barrier(0);

  const char* aRow0 = lds + l16 * 4096;
  const char* aRow1 = lds + (16 + l16) * 4096;
  const int aE = (((quad * 2) ^ (l16 & 7)) << 4);

#pragma unroll
  for (int r = 0; r < 16; ++r) {
    const int Rk = kh * 16 + r;
    float4 a00 = *(const float4*)(const void*)(aRow0 + Rk * 128 + aE);
    float4 a01 = *(const float4*)(const void*)(aRow0 + Rk * 128 + (aE ^ 16));
    float4 a10 = *(const float4*)(const void*)(aRow1 + Rk * 128 + aE);
    float4 a11 = *(const float4*)(const void*)(aRow1 + Rk * 128 + (aE ^ 16));
    bf16x8 ah0, al0, ah1, al1;
    cvt_split(a00, a01, ah0, al0);
    cvt_split(a10, a11, ah1, al1);
    const int s = r % 3;
#pragma unroll
    for (int t = 0; t < 3; t++) {
      acc[0][t] =
          __builtin_amdgcn_mfma_f32_16x16x32_bf16(ah0, Bh[s][t], acc[0][t], 0, 0, 0);
      acc[0][t] =
          __builtin_amdgcn_mfma_f32_16x16x32_bf16(ah0, Bl[s][t], acc[0][t], 0, 0, 0);
      acc[0][t] =
          __builtin_amdgcn_mfma_f32_16x16x32_bf16(al0, Bh[s][t], acc[0][t], 0, 0, 0);
      acc[1][t] =
          __builtin_amdgcn_mfma_f32_16x16x32_bf16(ah1, Bh[s][t], acc[1][t], 0, 0, 0);
      acc[1][t] =
          __builtin_amdgcn_mfma_f32_16x16x32_bf16(ah1, Bl[s][t], acc[1][t], 0, 0, 0);
      acc[1][t] =
          __builtin_amdgcn_mfma_f32_16x16x32_bf16(al1, Bh[s][t], acc[1][t], 0, 0, 0);
    }
    if (r + 3 < 16) LOADB((r + 3) % 3, r + 3);
    asm volatile("" ::: "memory");
  }
#undef LOADB

  // kh-merge (reuse A-LDS; fully consumed) + epilogue. No early returns.
  f32x4(*red)[64][6] = (f32x4(*)[64][6])lds;   // 24.5 KB @ base
  float* ldsQ = (float*)(lds + 98304);         // 8 KB, disjoint from red
  __syncthreads();
  if (kh == 1) {
#pragma unroll
    for (int f = 0; f < 2; f++)
#pragma unroll
      for (int t = 0; t < 3; t++) red[nh][lane][f * 3 + t] = acc[f][t];
  }
  __syncthreads();
  if (kh == 0) {
#pragma unroll
    for (int f = 0; f < 2; f++)
#pragma unroll
      for (int t = 0; t < 3; t++) acc[f][t] += red[nh][lane][f * 3 + t];
    const int bb = rowBase >> 12;
#pragma unroll
    for (int f = 0; f < 2; f++)
#pragma unroll
      for (int t = 0; t < 3; t++) {
        int nt = nh * 3 + t;
        int n = nt * 16 + l16;
        if (n < 64) {                          // Q -> LDS only (never global)
          float bias = bq[n];
#pragma unroll
          for (int rr = 0; rr < 4; rr++)
            ldsQ[(f * 16 + quad * 4 + rr) * 64 + n] = acc[f][t][rr] + bias;
        } else {
          int mat = n >> 6;
          int col = n & 63;
          float bias = (mat == 1) ? bk[col] : bv[col];
          float* dst = qkv + (size_t)mat * MROWS * DDIM +
                       (size_t)(rowBase + f * 16 + quad * 4) * DDIM + col;
          float vs = 0.f;
#pragma unroll
          for (int rr = 0; rr < 4; rr++) {
            float val = acc[f][t][rr] + bias;
            dst[rr * DDIM] = val;
            vs += val;
          }
          if (nt >= 8) {                       // V tiles -> Vsum
            vs += __shfl_xor(vs, 16, 64);
            vs += __shfl_xor(vs, 32, 64);
            if (quad == 0) atomicAdd(&Vsum[bb * DDIM + (n - 128)], vs);
          }
        }
      }
  }
  __threadfence();                             // release K/V/Vsum
  cg::this_grid().sync();

  // ---- Phase C: attention (32 queries/block, 16 lanes/query, float4) ----
  {
    const float* Kf = qkv + (size_t)MROWS * DDIM;
    const float* Vf = qkv + (size_t)2 * MROWS * DDIM;
    const int l16c = tid & 15;
    const int qloc = tid >> 4;                // 0..31
    const int qidx = rowBase + qloc;
    const int b = qidx >> 12;
    const int i = qidx & 4095;

    float4 q = *(const float4*)(const void*)(ldsQ + qloc * 64 + 4 * l16c);
    float sc[5];
    float4 vv[5];
    bool val[5];
#pragma unroll
    for (int w = 0; w < 5; w++) {
      int j = i + 2 * w - 4;                  // DIL*(w - WIN/2), DIL=2
      val[w] = (j >= 0) && (j < S_LEN);
      int jj = val[w] ? j : i;
      size_t off = (size_t)(b * S_LEN + jj) * DDIM + 4 * l16c;
      float4 kk = *(const float4*)(const void*)(Kf + off);
      vv[w] = *(const float4*)(const void*)(Vf + off);
      float p = q.x * kk.x + q.y * kk.y + q.z * kk.z + q.w * kk.w;
      p += __shfl_xor(p, 1, 64);
      p += __shfl_xor(p, 2, 64);
      p += __shfl_xor(p, 4, 64);
      p += __shfl_xor(p, 8, 64);
      sc[w] = p;
    }

    float mx = 0.f;                           // background score 0 in the max
#pragma unroll
    for (int w = 0; w < 5; w++)
      if (val[w]) mx = fmaxf(mx, sc[w]);

    float denom = 0.f;
    float4 accv = {0.f, 0.f, 0.f, 0.f}, vsel = {0.f, 0.f, 0.f, 0.f};
    int nval = 0;
#pragma unroll
    for (int w = 0; w < 5; w++)
      if (val[w]) {
        float pexp = __expf(sc[w] - mx);
        denom += pexp;
        accv.x += pexp * vv[w].x;
        accv.y += pexp * vv[w].y;
        accv.z += pexp * vv[w].z;
        accv.w += pexp * vv[w].w;
        vsel.x += vv[w].x;
        vsel.y += vv[w].y;
        vsel.z += vv[w].z;
        vsel.w += vv[w].w;
        nval++;
      }
    float pbg = __expf(-mx);
    denom += pbg * (float)(S_LEN - nval);
    float4 vsm = *(const float4*)(const void*)(Vsum + b * DDIM + 4 * l16c);
    accv.x += pbg * (vsm.x - vsel.x);
    accv.y += pbg * (vsm.y - vsel.y);
    accv.z += pbg * (vsm.z - vsel.z);
    accv.w += pbg * (vsm.w - vsel.w);

    float4 o = {accv.x / denom, accv.y / denom, accv.z / denom,
                accv.w / denom};
    *(float4*)(void*)(out + (size_t)qidx * DDIM + 4 * l16c) = o;
  }
}

// ===========================================================================
// FALLBACK path (3 kernels, v10) — used only if cooperative launch errors.
// ===========================================================================
__global__ __launch_bounds__(256) void pack_w_kernel(
    const float* __restrict__ Wq, const float* __restrict__ Wk,
    const float* __restrict__ Wv, bf16* __restrict__ Wt2_hi,
    bf16* __restrict__ Wt2_lo, float* __restrict__ Vsum) {
  __shared__ float tile[64 * 65];
  const int mat = blockIdx.x >> 4;
  const int kb = blockIdx.x & 15;
  const int t = threadIdx.x;
  if (blockIdx.x == 0 && t < NBATCH * DDIM) Vsum[t] = 0.f;
  const float* W = (mat == 0) ? Wq : ((mat == 1) ? Wk : Wv);

#pragma unroll
  for (int i = 0; i < 4; i++) {
    int F = (i * 256 + t) * 4;
    int k = F >> 6;
    int n4 = F & 63;
    float4 v = *(const float4*)(const void*)(W + (size_t)(kb * 64 + k) * 64 + n4);
    tile[(n4 + 0) * 65 + k] = v.x;
    tile[(n4 + 1) * 65 + k] = v.y;
    tile[(n4 + 2) * 65 + k] = v.z;
    tile[(n4 + 3) * 65 + k] = v.w;
  }
  __syncthreads();

#pragma unroll
  for (int it = 0; it < 2; it++) {
    int uidx = it * 256 + t;
    int nl = uidx >> 3;
    int j_half = (uidx >> 2) & 1;
    int pp_k = uidx & 3;
    int ng = mat * 64 + nl;
    int n2 = ng >> 1;
    int sp = ((ng & 1) * 4 + pp_k) ^ (n2 & 7);
    int unit = n2 * 8 + sp;
    int j = kb * 2 + j_half;
    frag_u h, l;
#pragma unroll
    for (int e = 0; e < 8; e++) {
      float v = tile[nl * 65 + j_half * 32 + pp_k * 8 + e];
      bf16 hh = __float2bfloat16(v);
      h.e[e] = hh;
      l.e[e] = __float2bfloat16(v - __bfloat162float(hh));
    }
    size_t ob = (size_t)j * 6144 + unit * 8;
    *(bf16x8*)(void*)(Wt2_hi + ob) = h.v;
    *(bf16x8*)(void*)(Wt2_lo + ob) = l.v;
  }
}

__global__ __launch_bounds__(512, 2) void qkv_gemm_kernel(
    const float* __restrict__ x, const bf16* __restrict__ Wt2_hi,
    const bf16* __restrict__ Wt2_lo, const float* __restrict__ bq,
    const float* __restrict__ bk, const float* __restrict__ bv,
    float* __restrict__ qkv, float* __restrict__ Vsum) {
  __shared__ __align__(16) char lds[131072];
  const int tid = threadIdx.x;
  const int lane = tid & 63;
  const int wave = tid >> 6;
  const int nh = wave & 3;
  const int kh = wave >> 2;
  const int quad = lane >> 4;
  const int l16 = lane & 15;
  const int rowBase = blockIdx.x * 32;

  const int sp = ((l16 & 1) * 4 + quad) ^ ((l16 >> 1) & 7);
  const int loff = ((l16 >> 1) * 8 + sp) * 8;
  const bf16* bhp = Wt2_hi + (size_t)kh * 98304 + nh * 1536 + loff;
  const bf16* blp = Wt2_lo + (size_t)kh * 98304 + nh * 1536 + loff;

  bf16x8 Bh[3][3], Bl[3][3];
  f32x4 acc[2][3];
#pragma unroll
  for (int f = 0; f < 2; f++)
#pragma unroll
    for (int t = 0; t < 3; t++) acc[f][t] = (f32x4){0.f, 0.f, 0.f, 0.f};

#define LOADB(s, r)                                                          \
  {                                                                          \
    const bf16* _h = bhp + (size_t)(r) * 6144;                               \
    const bf16* _l = blp + (size_t)(r) * 6144;                               \
    Bh[s][0] = *(const bf16x8*)(const void*)(_h);                            \
    Bh[s][1] = *(const bf16x8*)(const void*)(_h + 512);                      \
    Bh[s][2] = *(const bf16x8*)(const void*)(_h + 1024);                     \
    Bl[s][0] = *(const bf16x8*)(const void*)(_l);                            \
    Bl[s][1] = *(const bf16x8*)(const void*)(_l + 512);                      \
    Bl[s][2] = *(const bf16x8*)(const void*)(_l + 1024);                     \
  }

#pragma unroll
  for (int i = 0; i < 16; i++) {
    const int Rl = (wave << 2) | (i >> 2);
    const int g = i & 3;
    const char* src = (const char*)x + (size_t)(rowBase + Rl) * 4096 +
                      (size_t)g * 1024 + ((lane ^ (Rl & 7)) << 4);
    async_ld16(src, lds + Rl * 4096 + g * 1024);
  }
  asm volatile("" ::: "memory");
  LOADB(0, 0);
  LOADB(1, 1);
  LOADB(2, 2);
  asm volatile("s_waitcnt vmcnt(18)" ::: "memory");
  __builtin_amdgcn_s_barrier();
  __builtin_amdgcn_sched_barrier(0);

  const char* aRow0 = lds + l16 * 4096;
  const char* aRow1 = lds + (16 + l16) * 4096;
  const int aE = (((quad * 2) ^ (l16 & 7)) << 4);

#pragma unroll
  for (int r = 0; r < 16; ++r) {
    const int Rk = kh * 16 + r;
    float4 a00 = *(const float4*)(const void*)(aRow0 + Rk * 128 + aE);
    float4 a01 = *(const float4*)(const void*)(aRow0 + Rk * 128 + (aE ^ 16));
    float4 a10 = *(const float4*)(const void*)(aRow1 + Rk * 128 + aE);
    float4 a11 = *(const float4*)(const void*)(aRow1 + Rk * 128 + (aE ^ 16));
    bf16x8 ah0, al0, ah1, al1;
    cvt_split(a00, a01, ah0, al0);
    cvt_split(a10, a11, ah1, al1);
    const int s = r % 3;
#pragma unroll
    for (int t = 0; t < 3; t++) {
      acc[0][t] =
          __builtin_amdgcn_mfma_f32_16x16x32_bf16(ah0, Bh[s][t], acc[0][t], 0, 0, 0);
      acc[0][t] =
          __builtin_amdgcn_mfma_f32_16x16x32_bf16(ah0, Bl[s][t], acc[0][t], 0, 0, 0);
      acc[0][t] =
          __builtin_amdgcn_mfma_f32_16x16x32_bf16(al0, Bh[s][t], acc[0][t], 0, 0, 0);
      acc[1][t] =
          __builtin_amdgcn_mfma_f32_16x16x32_bf16(ah1, Bh[s][t], acc[1][t], 0, 0, 0);
      acc[1][t] =
          __builtin_amdgcn_mfma_f32_16x16x32_bf16(ah1, Bl[s][t], acc[1][t], 0, 0, 0);
      acc[1][t] =
          __builtin_amdgcn_mfma_f32_16x16x32_bf16(al1, Bh[s][t], acc[1][t], 0, 0, 0);
    }
    if (r + 3 < 16) LOADB((r + 3) % 3, r + 3);
    asm volatile("" ::: "memory");
  }
#undef LOADB

  f32x4(*red)[64][6] = (f32x4(*)[64][6])lds;
  __syncthreads();
  if (kh == 1) {
#pragma unroll
    for (int f = 0; f < 2; f++)
#pragma unroll
      for (int t = 0; t < 3; t++) red[nh][lane][f * 3 + t] = acc[f][t];
  }
  __syncthreads();
  if (kh == 1) return;
#pragma unroll
  for (int f = 0; f < 2; f++)
#pragma unroll
    for (int t = 0; t < 3; t++) acc[f][t] += red[nh][lane][f * 3 + t];

  const int bb = rowBase >> 12;
#pragma unroll
  for (int f = 0; f < 2; f++)
#pragma unroll
    for (int t = 0; t < 3; t++) {
      int nt = nh * 3 + t;
      int n = nt * 16 + l16;
      int mat = n >> 6;
      int col = n & 63;
      float bias = (mat == 0) ? bq[col] : ((mat == 1) ? bk[col] : bv[col]);
      float* dst = qkv + (size_t)mat * MROWS * DDIM +
                   (size_t)(rowBase + f * 16 + quad * 4) * DDIM + col;
      float vs = 0.f;
#pragma unroll
      for (int rr = 0; rr < 4; rr++) {
        float val = acc[f][t][rr] + bias;
        dst[rr * DDIM] = val;
        vs += val;
      }
      if (nt >= 8) {
        vs += __shfl_xor(vs, 16, 64);
        vs += __shfl_xor(vs, 32, 64);
        if (quad == 0) atomicAdd(&Vsum[bb * DDIM + (n - 128)], vs);
      }
    }
}

__global__ __launch_bounds__(256) void attn_kernel(
    const float* __restrict__ qkv, const float* __restrict__ Vsum,
    float* __restrict__ out) {
  const float* Qf = qkv;
  const float* Kf = qkv + (size_t)MROWS * DDIM;
  const float* Vf = qkv + (size_t)2 * MROWS * DDIM;
  int l = threadIdx.x & 31;
  int qidx = blockIdx.x * 8 + (threadIdx.x >> 5);
  int b = qidx >> 12;
  int i = qidx & 4095;

  float2 q = *(const float2*)(const void*)(Qf + (size_t)qidx * DDIM + 2 * l);
  float sc[5];
  float2 vv[5];
  bool val[5];
#pragma unroll
  for (int w = 0; w < 5; w++) {
    int j = i + 2 * w - 4;
    val[w] = (j >= 0) && (j < S_LEN);
    int jj = val[w] ? j : i;
    size_t off = (size_t)(b * S_LEN + jj) * DDIM + 2 * l;
    float2 kk = *(const float2*)(const void*)(Kf + off);
    vv[w] = *(const float2*)(const void*)(Vf + off);
    float p = q.x * kk.x + q.y * kk.y;
#pragma unroll
    for (int d = 1; d < 32; d <<= 1) p += __shfl_xor(p, d, 64);
    sc[w] = p;
  }

  float mx = 0.f;
#pragma unroll
  for (int w = 0; w < 5; w++)
    if (val[w]) mx = fmaxf(mx, sc[w]);

  float denom = 0.f;
  float2 accv = {0.f, 0.f}, vsel = {0.f, 0.f};
  int nval = 0;
#pragma unroll
  for (int w = 0; w < 5; w++)
    if (val[w]) {
      float pexp = __expf(sc[w] - mx);
      denom += pexp;
      accv.x += pexp * vv[w].x;
      accv.y += pexp * vv[w].y;
      vsel.x += vv[w].x;
      vsel.y += vv[w].y;
      nval++;
    }
  float pbg = __expf(-mx);
  denom += pbg * (float)(S_LEN - nval);
  float2 vsm = *(const float2*)(const void*)(Vsum + b * DDIM + 2 * l);
  accv.x += pbg * (vsm.x - vsel.x);
  accv.y += pbg * (vsm.y - vsel.y);

  float2 o = {accv.x / denom, accv.y / denom};
  *(float2*)(void*)(out + (size_t)qidx * DDIM + 2 * l) = o;
}

// ---------------------------------------------------------------------------
extern "C" void kernel_launch(void* const* d_in, const int* in_sizes, int n_in,
                              void* d_out, int out_size, void* d_ws,
                              size_t ws_size, hipStream_t stream) {
  const float* x = (const float*)d_in[0];
  const float* Wq = (const float*)d_in[1];
  const float* bq = (const float*)d_in[2];
  const float* Wk = (const float*)d_in[3];
  const float* bk = (const float*)d_in[4];
  const float* Wv = (const float*)d_in[5];
  const float* bv = (const float*)d_in[6];
  float* out = (float*)d_out;

  char* ws = (char*)d_ws;
  bf16* Wt2_hi = (bf16*)ws;                   // 393216 B
  bf16* Wt2_lo = (bf16*)(ws + 393216);        // 393216 B
  float* qkv = (float*)(ws + 786432);         // 6291456 B
  float* Vsum = (float*)(ws + 786432 + 6291456);  // 512 B

  void* args[12] = {(void*)&x,      (void*)&Wq,     (void*)&bq,
                    (void*)&Wk,     (void*)&bk,     (void*)&Wv,
                    (void*)&bv,     (void*)&Wt2_hi, (void*)&Wt2_lo,
                    (void*)&qkv,    (void*)&Vsum,   (void*)&out};
  hipError_t err = hipLaunchCooperativeKernel((const void*)fused_kernel,
                                              dim3(256), dim3(512), args, 0,
                                              stream);
  if (err != hipSuccess) {
    // fallback: 3-kernel v10 pipeline
    hipLaunchKernelGGL(pack_w_kernel, dim3(48), dim3(256), 0, stream, Wq, Wk,
                       Wv, Wt2_hi, Wt2_lo, Vsum);
    hipLaunchKernelGGL(qkv_gemm_kernel, dim3(256), dim3(512), 0, stream, x,
                       Wt2_hi, Wt2_lo, bq, bk, bv, qkv, Vsum);
    hipLaunchKernelGGL(attn_kernel, dim3(1024), dim3(256), 0, stream, qkv,
                       Vsum, out);
  }
}

// Round 7
// 112.859 us; speedup vs baseline: 2.4567x; 2.4567x over previous
//
#include <hip/hip_runtime.h>
#include <hip/hip_bf16.h>

typedef __hip_bfloat16 bf16;
typedef short bf16x8 __attribute__((ext_vector_type(8)));
typedef float f32x4 __attribute__((ext_vector_type(4)));

#define S_LEN 4096
#define NBATCH 2
#define EDIM 1024
#define DDIM 64
#define MROWS (NBATCH * S_LEN)   // 8192

#define GLOBAL_AS __attribute__((address_space(1)))
#define LDS_AS __attribute__((address_space(3)))

union frag_u { bf16x8 v; bf16 e[8]; };

// async 16B global -> LDS (dest wave-uniform; HW adds lane*16; src per-lane)
__device__ __forceinline__ void async_ld16(const void* gp, void* lp) {
  __builtin_amdgcn_global_load_lds((const GLOBAL_AS void*)gp,
                                   (LDS_AS void*)lp, 16, 0, 0);
}

// f32x8 -> split bf16 hi/lo fragments (x ~= hi + lo, rel err ~2^-17)
__device__ __forceinline__ void cvt_split(const float4& a, const float4& b,
                                          bf16x8& hi, bf16x8& lo) {
  float v[8] = {a.x, a.y, a.z, a.w, b.x, b.y, b.z, b.w};
  frag_u h, l;
#pragma unroll
  for (int e = 0; e < 8; e++) {
    bf16 hh = __float2bfloat16(v[e]);
    h.e[e] = hh;
    l.e[e] = __float2bfloat16(v[e] - __bfloat162float(hh));
  }
  hi = h.v;
  lo = l.v;
}

// ---------------------------------------------------------------------------
// Pack weights (f32, k-major [1024][64]) -> split-bf16 in ROUND-MAJOR
// order: Wt2[j=0..31][unit u=0..767][8 bf16], round j covers k in
// [j*32, j*32+32). Unit for (n, kk): n2 = n>>1, pp = (n&1)*4 + (kk>>3),
// sp = pp ^ (n2 & 7), u = n2*8 + sp, elem = kk&7. A round block = 12288 B.
// The gemm reads lane units DIRECTLY from global (each (nt, round) is a
// contiguous, fully-consumed 1 KB segment -> perfect coalescing, L2-hot).
// Grid 48 = 3 mats x 16 k-blocks. Block 0 zeroes Vsum.
// ---------------------------------------------------------------------------
__global__ __launch_bounds__(256) void pack_w_kernel(
    const float* __restrict__ Wq, const float* __restrict__ Wk,
    const float* __restrict__ Wv, bf16* __restrict__ Wt2_hi,
    bf16* __restrict__ Wt2_lo, float* __restrict__ Vsum) {
  __shared__ float tile[64 * 65];
  const int mat = blockIdx.x >> 4;
  const int kb = blockIdx.x & 15;             // 64-k block -> rounds 2kb,2kb+1
  const int t = threadIdx.x;
  if (blockIdx.x == 0 && t < NBATCH * DDIM) Vsum[t] = 0.f;
  const float* W = (mat == 0) ? Wq : ((mat == 1) ? Wk : Wv);

#pragma unroll
  for (int i = 0; i < 4; i++) {
    int F = (i * 256 + t) * 4;                // flat f32 idx in [0,4096)
    int k = F >> 6;
    int n4 = F & 63;
    float4 v = *(const float4*)(const void*)(W + (size_t)(kb * 64 + k) * 64 + n4);
    tile[(n4 + 0) * 65 + k] = v.x;
    tile[(n4 + 1) * 65 + k] = v.y;
    tile[(n4 + 2) * 65 + k] = v.z;
    tile[(n4 + 3) * 65 + k] = v.w;
  }
  __syncthreads();

  // 512 units (hi+lo written together): nl, j_half, pp_k
#pragma unroll
  for (int it = 0; it < 2; it++) {
    int uidx = it * 256 + t;
    int nl = uidx >> 3;
    int j_half = (uidx >> 2) & 1;
    int pp_k = uidx & 3;
    int ng = mat * 64 + nl;                   // global n in [0,192)
    int n2 = ng >> 1;
    int sp = ((ng & 1) * 4 + pp_k) ^ (n2 & 7);
    int unit = n2 * 8 + sp;
    int j = kb * 2 + j_half;
    frag_u h, l;
#pragma unroll
    for (int e = 0; e < 8; e++) {
      float v = tile[nl * 65 + j_half * 32 + pp_k * 8 + e];
      bf16 hh = __float2bfloat16(v);
      h.e[e] = hh;
      l.e[e] = __float2bfloat16(v - __bfloat162float(hh));
    }
    size_t ob = (size_t)j * 6144 + unit * 8;
    *(bf16x8*)(void*)(Wt2_hi + ob) = h.v;
    *(bf16x8*)(void*)(Wt2_lo + ob) = l.v;
  }
}

// ---------------------------------------------------------------------------
// Fused QKV GEMM v12 — 16-ROW BLOCKS, 2 BLOCKS/CU (occupancy overlap).
// R6 post-mortem: cg grid.sync ~80us/sync at 256 blocks => fusion dead.
// v10 analysis: 1 block/CU (128 KB LDS) => the 5.2-us A-panel DMA prologue,
// the K-loop stalls and the epilogue all run SERIAL per CU — nothing hides
// them. Measured 32.3 us vs ~13-15 modeled.
// v12: halve the block (16 rows, A panel 64 KB LDS) -> 2 blocks/CU; block
// 2's staging/epilogue overlaps block 1's K-loop. To keep 4 waves/SIMD the
// kernel must stay <=128 VGPR: B-ring 3->2 slots, __launch_bounds__(512,4).
// Cost: B L2 traffic doubles (512 x 768 KB = 393 MB, ~11.4 us aggregate) —
// still well below the 32-us status quo.
// Structure per block: 8 waves = nh(0..3) x kh(0..1); wave = 16 rows x 3
// n-tiles, 9 MFMA/round, 16 rounds. Staging: wave stages 2 rows as 8x 1-KB
// contiguous bursts (v10 pattern, lane^(row&7) source swizzle). Prologue:
// 8 DMAs + 12 B-loads -> s_waitcnt vmcnt(12) + s_barrier. K-loop barrier-
// free: B reg ring-2 (L2-hot packed Wt2, issue at round end), swizzled
// ds_read_b128 A-frags (2-way = free), cvt_split, MFMA.
// MFMA f32_16x16x32_bf16 split-bf16 (xh*wh + xh*wl + xl*wh):
//   A[m][k]: m=lane&15, k=(lane>>4)*8+e | B[k][n]: n=lane&15, k=(lane>>4)*8+e
//   D[m][n]: m=(lane>>4)*4+r, n=lane&15
// ---------------------------------------------------------------------------
__global__ __launch_bounds__(512, 4) void qkv_gemm_kernel(
    const float* __restrict__ x, const bf16* __restrict__ Wt2_hi,
    const bf16* __restrict__ Wt2_lo, const float* __restrict__ bq,
    const float* __restrict__ bk, const float* __restrict__ bv,
    float* __restrict__ qkv, float* __restrict__ Vsum) {
  __shared__ __align__(16) char lds[65536];   // 16 rows x 4096 B (A panel)
  const int tid = threadIdx.x;
  const int lane = tid & 63;
  const int wave = tid >> 6;                  // 0..7
  const int nh = wave & 3;                    // n-group (3 n-tiles)
  const int kh = wave >> 2;                   // k-half
  const int quad = lane >> 4;
  const int l16 = lane & 15;
  const int rowBase = blockIdx.x * 16;

  // B lane pointer (pre-swizzled pack layout): unit = nt*512 + loff bf16
  const int sp = ((l16 & 1) * 4 + quad) ^ ((l16 >> 1) & 7);
  const int loff = ((l16 >> 1) * 8 + sp) * 8;
  const bf16* bhp = Wt2_hi + (size_t)kh * 98304 + nh * 1536 + loff;  // 16*6144
  const bf16* blp = Wt2_lo + (size_t)kh * 98304 + nh * 1536 + loff;

  bf16x8 Bh[2][3], Bl[2][3];                  // [slot][t], ring-2
  f32x4 acc[3];
#pragma unroll
  for (int t = 0; t < 3; t++) acc[t] = (f32x4){0.f, 0.f, 0.f, 0.f};

#define LOADB(s, r)                                                          \
  {                                                                          \
    const bf16* _h = bhp + (size_t)(r) * 6144;                               \
    const bf16* _l = blp + (size_t)(r) * 6144;                               \
    Bh[s][0] = *(const bf16x8*)(const void*)(_h);                            \
    Bh[s][1] = *(const bf16x8*)(const void*)(_h + 512);                      \
    Bh[s][2] = *(const bf16x8*)(const void*)(_h + 1024);                     \
    Bl[s][0] = *(const bf16x8*)(const void*)(_l);                            \
    Bl[s][1] = *(const bf16x8*)(const void*)(_l + 512);                      \
    Bl[s][2] = *(const bf16x8*)(const void*)(_l + 1024);                     \
  }

  // ---- stage A: wave w -> rows w*2, w*2+1; 4x 1-KB contiguous bursts/row.
  // Per-lane source XOR swizzle (low-3 chunk bits) = LDS image
  // LDS[R][c] = x[R][c ^ (R&7)] (same 1-KB address set, permuted lanes).
#pragma unroll
  for (int i = 0; i < 8; i++) {
    const int Rl = (wave << 1) | (i >> 2);
    const int g = i & 3;
    const char* src = (const char*)x + (size_t)(rowBase + Rl) * 4096 +
                      (size_t)g * 1024 + ((lane ^ (Rl & 7)) << 4);
    async_ld16(src, lds + Rl * 4096 + g * 1024);
  }
  asm volatile("" ::: "memory");              // DMAs strictly before B loads
  LOADB(0, 0);
  LOADB(1, 1);
  // own 8 DMAs retired (12 B loads may remain in flight); then cross-wave
  asm volatile("s_waitcnt vmcnt(12)" ::: "memory");
  __builtin_amdgcn_s_barrier();
  __builtin_amdgcn_sched_barrier(0);

  // A fragment base: row l16 (row&7 == l16&7)
  const char* aRow0 = lds + l16 * 4096;
  const int aE = (((quad * 2) ^ (l16 & 7)) << 4);

#pragma unroll
  for (int r = 0; r < 16; ++r) {
    const int Rk = kh * 16 + r;               // absolute K-round
    float4 a00 = *(const float4*)(const void*)(aRow0 + Rk * 128 + aE);
    float4 a01 = *(const float4*)(const void*)(aRow0 + Rk * 128 + (aE ^ 16));
    bf16x8 ah0, al0;
    cvt_split(a00, a01, ah0, al0);
    const int s = r & 1;
#pragma unroll
    for (int t = 0; t < 3; t++) {
      acc[t] =
          __builtin_amdgcn_mfma_f32_16x16x32_bf16(ah0, Bh[s][t], acc[t], 0, 0, 0);
      acc[t] =
          __builtin_amdgcn_mfma_f32_16x16x32_bf16(ah0, Bl[s][t], acc[t], 0, 0, 0);
      acc[t] =
          __builtin_amdgcn_mfma_f32_16x16x32_bf16(al0, Bh[s][t], acc[t], 0, 0, 0);
    }
    if (r + 2 < 16) LOADB((r + 2) & 1, r + 2);  // B issue at round end
    asm volatile("" ::: "memory");              // pin issue position
  }
#undef LOADB

  // merge k-halves (reuse A-LDS; A fully consumed): kh=1 export, kh=0 absorb
  f32x4(*red)[64][3] = (f32x4(*)[64][3])lds;   // 12.3 KB < 64 KB
  __syncthreads();                             // all waves done reading A
  if (kh == 1) {
#pragma unroll
    for (int t = 0; t < 3; t++) red[nh][lane][t] = acc[t];
  }
  __syncthreads();
  if (kh == 1) return;
#pragma unroll
  for (int t = 0; t < 3; t++) acc[t] += red[nh][lane][t];

  // epilogue: bias + store + V column sums
  const int bb = rowBase >> 12;
#pragma unroll
  for (int t = 0; t < 3; t++) {
    int nt = nh * 3 + t;
    int n = nt * 16 + l16;
    int mat = n >> 6;
    int col = n & 63;
    float bias = (mat == 0) ? bq[col] : ((mat == 1) ? bk[col] : bv[col]);
    float* dst = qkv + (size_t)mat * MROWS * DDIM +
                 (size_t)(rowBase + quad * 4) * DDIM + col;
    float vs = 0.f;
#pragma unroll
    for (int rr = 0; rr < 4; rr++) {
      float val = acc[t][rr] + bias;
      dst[rr * DDIM] = val;
      vs += val;
    }
    if (nt >= 8) {                            // V tiles -> Vsum
      vs += __shfl_xor(vs, 16, 64);
      vs += __shfl_xor(vs, 32, 64);
      if (quad == 0) atomicAdd(&Vsum[bb * DDIM + (n - 128)], vs);
    }
  }
}

// ---------------------------------------------------------------------------
// Attention: 2 queries per wave, 32 lanes each, lane owns a float2 dim-pair.
// Full-row softmax collapses to: 5 window exps + (S - nvalid) background
// exp(0-m) terms; background numerator = Vsum - sum(window V).
// ---------------------------------------------------------------------------
__global__ __launch_bounds__(256) void attn_kernel(
    const float* __restrict__ qkv, const float* __restrict__ Vsum,
    float* __restrict__ out) {
  const float* Qf = qkv;
  const float* Kf = qkv + (size_t)MROWS * DDIM;
  const float* Vf = qkv + (size_t)2 * MROWS * DDIM;
  int l = threadIdx.x & 31;
  int qidx = blockIdx.x * 8 + (threadIdx.x >> 5);
  int b = qidx >> 12;
  int i = qidx & 4095;

  float2 q = *(const float2*)(const void*)(Qf + (size_t)qidx * DDIM + 2 * l);
  float sc[5];
  float2 vv[5];
  bool val[5];
#pragma unroll
  for (int w = 0; w < 5; w++) {
    int j = i + 2 * w - 4;                    // DIL*(w - WIN/2), DIL=2
    val[w] = (j >= 0) && (j < S_LEN);
    int jj = val[w] ? j : i;
    size_t off = (size_t)(b * S_LEN + jj) * DDIM + 2 * l;
    float2 kk = *(const float2*)(const void*)(Kf + off);
    vv[w] = *(const float2*)(const void*)(Vf + off);
    float p = q.x * kk.x + q.y * kk.y;
#pragma unroll
    for (int d = 1; d < 32; d <<= 1) p += __shfl_xor(p, d, 64);
    sc[w] = p;
  }

  float mx = 0.f;                             // background score 0 in the max
#pragma unroll
  for (int w = 0; w < 5; w++)
    if (val[w]) mx = fmaxf(mx, sc[w]);

  float denom = 0.f;
  float2 accv = {0.f, 0.f}, vsel = {0.f, 0.f};
  int nval = 0;
#pragma unroll
  for (int w = 0; w < 5; w++)
    if (val[w]) {
      float pexp = __expf(sc[w] - mx);
      denom += pexp;
      accv.x += pexp * vv[w].x;
      accv.y += pexp * vv[w].y;
      vsel.x += vv[w].x;
      vsel.y += vv[w].y;
      nval++;
    }
  float pbg = __expf(-mx);
  denom += pbg * (float)(S_LEN - nval);
  float2 vsm = *(const float2*)(const void*)(Vsum + b * DDIM + 2 * l);
  accv.x += pbg * (vsm.x - vsel.x);
  accv.y += pbg * (vsm.y - vsel.y);

  float2 o = {accv.x / denom, accv.y / denom};
  *(float2*)(void*)(out + (size_t)qidx * DDIM + 2 * l) = o;
}

// ---------------------------------------------------------------------------
extern "C" void kernel_launch(void* const* d_in, const int* in_sizes, int n_in,
                              void* d_out, int out_size, void* d_ws,
                              size_t ws_size, hipStream_t stream) {
  const float* x = (const float*)d_in[0];
  const float* Wq = (const float*)d_in[1];
  const float* bq = (const float*)d_in[2];
  const float* Wk = (const float*)d_in[3];
  const float* bk = (const float*)d_in[4];
  const float* Wv = (const float*)d_in[5];
  const float* bv = (const float*)d_in[6];
  float* out = (float*)d_out;

  char* ws = (char*)d_ws;
  bf16* Wt2_hi = (bf16*)ws;                   // 32*6144*2 = 393216 B
  bf16* Wt2_lo = (bf16*)(ws + 393216);        // 393216 B
  float* qkv = (float*)(ws + 786432);         // 3*8192*64*4 = 6291456 B
  float* Vsum = (float*)(ws + 786432 + 6291456);  // 512 B
  // total workspace ~7.1 MB

  hipLaunchKernelGGL(pack_w_kernel, dim3(48), dim3(256), 0, stream, Wq, Wk, Wv,
                     Wt2_hi, Wt2_lo, Vsum);
  hipLaunchKernelGGL(qkv_gemm_kernel, dim3(512), dim3(512), 0, stream, x,
                     Wt2_hi, Wt2_lo, bq, bk, bv, qkv, Vsum);
  hipLaunchKernelGGL(attn_kernel, dim3(1024), dim3(256), 0, stream, qkv, Vsum,
                     out);
}